// Round 6
// baseline (442.842 us; speedup 1.0000x reference)
//
#include <hip/hip_runtime.h>
#include <hip/hip_bf16.h>

#define NROW 8192
#define INF_ 512
#define OUTF 64

typedef __attribute__((ext_vector_type(4))) float  f32x4;
typedef __attribute__((ext_vector_type(4))) float  fx4;
typedef __attribute__((ext_vector_type(4))) int    i32x4;
typedef __attribute__((ext_vector_type(8))) short  bf16x8;

static __device__ __forceinline__ unsigned short f2bf(float x) {
  union { float f; unsigned int u; } c; c.f = x;
  unsigned int u = c.u;
  unsigned int r = (u + 0x7fffu + ((u >> 16) & 1u)) >> 16;
  return (unsigned short)r;
}
static __device__ __forceinline__ float bf2f(unsigned short h) {
  union { unsigned int u; float f; } c; c.u = ((unsigned int)h) << 16;
  return c.f;
}

// ---------------------------------------------------------------------------
// k0: Wa1/Wa2 = W @ a1, W @ a2 (fp32 exact score path) + pack W into
// split-bf16 B-fragment-linear layout.  Shared A/B placement convention:
// tile s, lane = pos + 16*kb, element b <-> contraction index kb*8+b.
// ---------------------------------------------------------------------------
__global__ __launch_bounds__(256) void k_prep0(
    const float* __restrict__ W, const float* __restrict__ a,
    float* __restrict__ Wa1, float* __restrict__ Wa2,
    unsigned short* __restrict__ Wbhi, unsigned short* __restrict__ Wblo) {
  int tid = threadIdx.x, blk = blockIdx.x;  // 8 blocks
  if (tid < 64) {
    int c = blk * 64 + tid;
    const float* wr = W + c * 64;
    float s1 = 0.f, s2 = 0.f;
#pragma unroll
    for (int k = 0; k < 64; ++k) {
      float w = wr[k];
      s1 += w * a[k];
      s2 += w * a[64 + k];
    }
    Wa1[c] = s1; Wa2[c] = s2;
  }
  int base = blk * 4096 + tid * 16;  // linear index into W (c*64+k)
#pragma unroll
  for (int e = 0; e < 16; ++e) {
    int idx = base + e;
    int c = idx >> 6, k = idx & 63;
    float w = W[idx];
    unsigned short h = f2bf(w);
    unsigned short l = f2bf(w - bf2f(h));
    int s = c >> 5, ji = c & 31;
    int lp = ((ji >> 3) << 4) | (k & 15);
    int n16 = k >> 4;
    size_t off = ((size_t)((s * 4 + n16) * 64 + lp)) * 8 + (ji & 7);
    Wbhi[off] = h; Wblo[off] = l;
  }
}

// ---------------------------------------------------------------------------
// k1 (fused): h = X @ W via split-bf16 MFMA (hi*hi + hi*lo + lo*hi) with
// in-register fp32->hi/lo split of X, PLUS exact fp32 f1=X@Wa1, f2=X@Wa2.
// Writes h as bf16 in B-fragment-linear layout HB[(tile*4+n)*64+lane]*8+b.
// ---------------------------------------------------------------------------
__global__ __launch_bounds__(256) void k_hgemm(
    const float* __restrict__ X,
    const float* __restrict__ Wa1, const float* __restrict__ Wa2,
    const unsigned short* __restrict__ Wbhi, const unsigned short* __restrict__ Wblo,
    unsigned short* __restrict__ HB,
    float* __restrict__ f1, float* __restrict__ f2) {
  int tid = threadIdx.x, wave = tid >> 6, lane = tid & 63;
  int row0 = blockIdx.x * 64 + wave * 16;
  int cl = lane & 15, kb = lane >> 4;
  f32x4 acc0 = {0.f,0.f,0.f,0.f}, acc1 = {0.f,0.f,0.f,0.f};
  f32x4 acc2 = {0.f,0.f,0.f,0.f}, acc3 = {0.f,0.f,0.f,0.f};
  float s1 = 0.f, s2 = 0.f;
  const float* xrow = X + (size_t)(row0 + cl) * INF_ + kb * 8;
  const bf16x8* BH = (const bf16x8*)Wbhi + lane;
  const bf16x8* BL = (const bf16x8*)Wblo + lane;
#pragma unroll 4
  for (int s = 0; s < 16; ++s) {
    fx4 x0 = *(const fx4*)(xrow + s * 32);
    fx4 x1 = *(const fx4*)(xrow + s * 32 + 4);
    const float* wp1 = Wa1 + kb * 8 + s * 32;
    const float* wp2 = Wa2 + kb * 8 + s * 32;
    fx4 w10 = *(const fx4*)(wp1), w11 = *(const fx4*)(wp1 + 4);
    fx4 w20 = *(const fx4*)(wp2), w21 = *(const fx4*)(wp2 + 4);
    bf16x8 ah, al;
#pragma unroll
    for (int e = 0; e < 4; ++e) {
      float xv = x0[e];
      unsigned short h = f2bf(xv);
      unsigned short l = f2bf(xv - bf2f(h));
      ah[e] = (short)h; al[e] = (short)l;
      s1 += xv * w10[e]; s2 += xv * w20[e];
    }
#pragma unroll
    for (int e = 0; e < 4; ++e) {
      float xv = x1[e];
      unsigned short h = f2bf(xv);
      unsigned short l = f2bf(xv - bf2f(h));
      ah[4 + e] = (short)h; al[4 + e] = (short)l;
      s1 += xv * w11[e]; s2 += xv * w21[e];
    }
    bf16x8 bh0 = BH[(s * 4 + 0) * 64], bl0 = BL[(s * 4 + 0) * 64];
    bf16x8 bh1 = BH[(s * 4 + 1) * 64], bl1 = BL[(s * 4 + 1) * 64];
    bf16x8 bh2 = BH[(s * 4 + 2) * 64], bl2 = BL[(s * 4 + 2) * 64];
    bf16x8 bh3 = BH[(s * 4 + 3) * 64], bl3 = BL[(s * 4 + 3) * 64];
    acc0 = __builtin_amdgcn_mfma_f32_16x16x32_bf16(ah, bh0, acc0, 0, 0, 0);
    acc0 = __builtin_amdgcn_mfma_f32_16x16x32_bf16(ah, bl0, acc0, 0, 0, 0);
    acc0 = __builtin_amdgcn_mfma_f32_16x16x32_bf16(al, bh0, acc0, 0, 0, 0);
    acc1 = __builtin_amdgcn_mfma_f32_16x16x32_bf16(ah, bh1, acc1, 0, 0, 0);
    acc1 = __builtin_amdgcn_mfma_f32_16x16x32_bf16(ah, bl1, acc1, 0, 0, 0);
    acc1 = __builtin_amdgcn_mfma_f32_16x16x32_bf16(al, bh1, acc1, 0, 0, 0);
    acc2 = __builtin_amdgcn_mfma_f32_16x16x32_bf16(ah, bh2, acc2, 0, 0, 0);
    acc2 = __builtin_amdgcn_mfma_f32_16x16x32_bf16(ah, bl2, acc2, 0, 0, 0);
    acc2 = __builtin_amdgcn_mfma_f32_16x16x32_bf16(al, bh2, acc2, 0, 0, 0);
    acc3 = __builtin_amdgcn_mfma_f32_16x16x32_bf16(ah, bh3, acc3, 0, 0, 0);
    acc3 = __builtin_amdgcn_mfma_f32_16x16x32_bf16(ah, bl3, acc3, 0, 0, 0);
    acc3 = __builtin_amdgcn_mfma_f32_16x16x32_bf16(al, bh3, acc3, 0, 0, 0);
  }
  s1 += __shfl_xor(s1, 16, 64); s1 += __shfl_xor(s1, 32, 64);
  s2 += __shfl_xor(s2, 16, 64); s2 += __shfl_xor(s2, 32, 64);
  if (kb == 0) { f1[row0 + cl] = s1; f2[row0 + cl] = s2; }
#pragma unroll
  for (int rr = 0; rr < 4; ++rr) {
    int i = row0 + kb * 4 + rr;       // C/D: row = (lane>>4)*4 + reg  [m89/m91]
    int jt = i >> 5, ji = i & 31;
    int lpb = ((ji >> 3) << 4) | cl;  // C/D: col = lane&15
    int b = ji & 7;
    HB[((size_t)((jt * 4 + 0) * 64 + lpb)) * 8 + b] = f2bf(acc0[rr]);
    HB[((size_t)((jt * 4 + 1) * 64 + lpb)) * 8 + b] = f2bf(acc1[rr]);
    HB[((size_t)((jt * 4 + 2) * 64 + lpb)) * 8 + b] = f2bf(acc2[rr]);
    HB[((size_t)((jt * 4 + 3) * 64 + lpb)) * 8 + b] = f2bf(acc3[rr]);
  }
}

// ---------------------------------------------------------------------------
// k2: main GAT kernel.  WG = 16 rows (512 WGs) x 8 waves (512 thr); wave w
// handles j-eighth (1024 j's = 32 tiles).  16 waves/CU for latency depth.
// Per 32-j tile: lane computes 8 masked exp-weights (= A-frag slots),
// 4 MFMAs accumulate O[16x64]; denominator = sum of bf16-rounded weights.
// ---------------------------------------------------------------------------
__global__ __launch_bounds__(512, 4) void k_gat(
    const int* __restrict__ adj, const float* __restrict__ f1,
    const float* __restrict__ f2, const unsigned short* __restrict__ HB,
    float* __restrict__ out) {
  __shared__ float Olds[8][16][64];
  __shared__ float Llds[8][16];
  int tid = threadIdx.x, wave = tid >> 6, lane = tid & 63;
  int rowbase = blockIdx.x * 16;
  int r = lane & 15, kb = lane >> 4;
  float f1r = f1[rowbase + r];
  f32x4 acc0 = {0.f,0.f,0.f,0.f}, acc1 = {0.f,0.f,0.f,0.f};
  f32x4 acc2 = {0.f,0.f,0.f,0.f}, acc3 = {0.f,0.f,0.f,0.f};
  float lsum = 0.f;
  const int jstart = wave * 1024;
  const size_t arow = (size_t)(rowbase + r) * NROW;
  const bf16x8* hb = (const bf16x8*)HB;

  // prologue: tile 0
  int j0 = jstart + kb * 8;
  i32x4 aa = __builtin_nontemporal_load((const i32x4*)(adj + arow + j0));
  i32x4 ab = __builtin_nontemporal_load((const i32x4*)(adj + arow + j0) + 1);
  fx4 fa = *(const fx4*)(f2 + j0);
  fx4 fb = *(const fx4*)(f2 + j0 + 4);
  int tile = jstart >> 5;
  bf16x8 B0 = hb[(tile * 4 + 0) * 64 + lane];
  bf16x8 B1 = hb[(tile * 4 + 1) * 64 + lane];
  bf16x8 B2 = hb[(tile * 4 + 2) * 64 + lane];
  bf16x8 B3 = hb[(tile * 4 + 3) * 64 + lane];

#pragma unroll 2
  for (int t = 0; t < 32; ++t) {
    int tn = (t + 1) & 31;  // last iter wraps to tile 0 (in-bounds, unused)
    int j0n = jstart + tn * 32 + kb * 8;
    int tn_tile = (jstart + tn * 32) >> 5;
    i32x4 naa = __builtin_nontemporal_load((const i32x4*)(adj + arow + j0n));
    i32x4 nab = __builtin_nontemporal_load((const i32x4*)(adj + arow + j0n) + 1);
    fx4 nfa = *(const fx4*)(f2 + j0n);
    fx4 nfb = *(const fx4*)(f2 + j0n + 4);
    bf16x8 nB0 = hb[(tn_tile * 4 + 0) * 64 + lane];
    bf16x8 nB1 = hb[(tn_tile * 4 + 1) * 64 + lane];
    bf16x8 nB2 = hb[(tn_tile * 4 + 2) * 64 + lane];
    bf16x8 nB3 = hb[(tn_tile * 4 + 3) * 64 + lane];

    bf16x8 A;
#define DO_W(slot, av, fv)                                   \
    {                                                        \
      float s_ = f1r + (fv);                                 \
      s_ = fmaxf(s_, 0.2f * s_);                             \
      float e_ = __expf(s_);                                 \
      e_ = (av) ? e_ : 0.0f;                                 \
      unsigned short h_ = f2bf(e_);                          \
      A[slot] = (short)h_;                                   \
      lsum += bf2f(h_);                                      \
    }
    DO_W(0, aa.x, fa.x) DO_W(1, aa.y, fa.y) DO_W(2, aa.z, fa.z) DO_W(3, aa.w, fa.w)
    DO_W(4, ab.x, fb.x) DO_W(5, ab.y, fb.y) DO_W(6, ab.z, fb.z) DO_W(7, ab.w, fb.w)
#undef DO_W
    acc0 = __builtin_amdgcn_mfma_f32_16x16x32_bf16(A, B0, acc0, 0, 0, 0);
    acc1 = __builtin_amdgcn_mfma_f32_16x16x32_bf16(A, B1, acc1, 0, 0, 0);
    acc2 = __builtin_amdgcn_mfma_f32_16x16x32_bf16(A, B2, acc2, 0, 0, 0);
    acc3 = __builtin_amdgcn_mfma_f32_16x16x32_bf16(A, B3, acc3, 0, 0, 0);
    aa = naa; ab = nab; fa = nfa; fb = nfb;
    B0 = nB0; B1 = nB1; B2 = nB2; B3 = nB3;
  }

  lsum += __shfl_xor(lsum, 16, 64);
  lsum += __shfl_xor(lsum, 32, 64);
#pragma unroll
  for (int rr = 0; rr < 4; ++rr) {
    Olds[wave][kb * 4 + rr][0 * 16 + r] = acc0[rr];
    Olds[wave][kb * 4 + rr][1 * 16 + r] = acc1[rr];
    Olds[wave][kb * 4 + rr][2 * 16 + r] = acc2[rr];
    Olds[wave][kb * 4 + rr][3 * 16 + r] = acc3[rr];
  }
  if (lane < 16) Llds[wave][lane] = lsum;
  __syncthreads();
#pragma unroll
  for (int e = 0; e < 2; ++e) {
    int idx = tid + e * 512;
    int rr = idx >> 6, n = idx & 63;
    float o = 0.f, l = 0.f;
#pragma unroll
    for (int wv = 0; wv < 8; ++wv) {
      o += Olds[wv][rr][n];
      l += Llds[wv][rr];
    }
    out[(size_t)(rowbase + rr) * OUTF + n] = o / l;
  }
}

extern "C" void kernel_launch(void* const* d_in, const int* in_sizes, int n_in,
                              void* d_out, int out_size, void* d_ws, size_t ws_size,
                              hipStream_t stream) {
  const float* X  = (const float*)d_in[0];
  const int* adj  = (const int*)d_in[1];
  const float* W  = (const float*)d_in[2];
  const float* a  = (const float*)d_in[3];
  float* out = (float*)d_out;

  char* ws = (char*)d_ws;
  float* f1            = (float*)(ws);                    // 32 KB
  float* f2            = (float*)(ws + 32768);            // 32 KB
  float* Wa1           = (float*)(ws + 65536);            // 2 KB
  float* Wa2           = (float*)(ws + 67584);            // 2 KB
  unsigned short* Wbhi = (unsigned short*)(ws + 69632);   // 64 KB
  unsigned short* Wblo = (unsigned short*)(ws + 135168);  // 64 KB
  unsigned short* HB   = (unsigned short*)(ws + 200704);  // 1 MB  (total ~1.25 MB)

  k_prep0<<<8, 256, 0, stream>>>(W, a, Wa1, Wa2, Wbhi, Wblo);
  k_hgemm<<<128, 256, 0, stream>>>(X, Wa1, Wa2, Wbhi, Wblo, HB, f1, f2);
  k_gat<<<512, 512, 0, stream>>>(adj, f1, f2, HB, out);
}

// Round 7
// 414.816 us; speedup vs baseline: 1.0676x; 1.0676x over previous
//
#include <hip/hip_runtime.h>
#include <hip/hip_bf16.h>

#define NROW 8192
#define INF_ 512
#define OUTF 64

typedef __attribute__((ext_vector_type(4))) float  f32x4;
typedef __attribute__((ext_vector_type(4))) float  fx4;
typedef __attribute__((ext_vector_type(4))) int    i32x4;
typedef __attribute__((ext_vector_type(8))) short  bf16x8;

static __device__ __forceinline__ unsigned short f2bf(float x) {
  union { float f; unsigned int u; } c; c.f = x;
  unsigned int u = c.u;
  unsigned int r = (u + 0x7fffu + ((u >> 16) & 1u)) >> 16;
  return (unsigned short)r;
}
static __device__ __forceinline__ float bf2f(unsigned short h) {
  union { unsigned int u; float f; } c; c.u = ((unsigned int)h) << 16;
  return c.f;
}

// ---------------------------------------------------------------------------
// k0: Wa1/Wa2 = W @ a1, W @ a2 (fp32 exact score path) + pack W into
// split-bf16 B-fragment-linear layout.  Shared A/B placement convention:
// tile s, lane = pos + 16*kb, element b <-> contraction index kb*8+b.
// ---------------------------------------------------------------------------
__global__ __launch_bounds__(256) void k_prep0(
    const float* __restrict__ W, const float* __restrict__ a,
    float* __restrict__ Wa1, float* __restrict__ Wa2,
    unsigned short* __restrict__ Wbhi, unsigned short* __restrict__ Wblo) {
  int tid = threadIdx.x, blk = blockIdx.x;  // 8 blocks
  if (tid < 64) {
    int c = blk * 64 + tid;
    const float* wr = W + c * 64;
    float s1 = 0.f, s2 = 0.f;
#pragma unroll
    for (int k = 0; k < 64; ++k) {
      float w = wr[k];
      s1 += w * a[k];
      s2 += w * a[64 + k];
    }
    Wa1[c] = s1; Wa2[c] = s2;
  }
  int base = blk * 4096 + tid * 16;  // linear index into W (c*64+k)
#pragma unroll
  for (int e = 0; e < 16; ++e) {
    int idx = base + e;
    int c = idx >> 6, k = idx & 63;
    float w = W[idx];
    unsigned short h = f2bf(w);
    unsigned short l = f2bf(w - bf2f(h));
    int s = c >> 5, ji = c & 31;
    int lp = ((ji >> 3) << 4) | (k & 15);
    int n16 = k >> 4;
    size_t off = ((size_t)((s * 4 + n16) * 64 + lp)) * 8 + (ji & 7);
    Wbhi[off] = h; Wblo[off] = l;
  }
}

// ---------------------------------------------------------------------------
// k1 (fused): h = X @ W via split-bf16 MFMA (hi*hi + hi*lo + lo*hi) with
// in-register fp32->hi/lo split of X, PLUS exact fp32 f1=X@Wa1, f2=X@Wa2.
// Writes h as bf16 in B-fragment-linear layout HB[(tile*4+n)*64+lane]*8+b.
// ---------------------------------------------------------------------------
__global__ __launch_bounds__(256) void k_hgemm(
    const float* __restrict__ X,
    const float* __restrict__ Wa1, const float* __restrict__ Wa2,
    const unsigned short* __restrict__ Wbhi, const unsigned short* __restrict__ Wblo,
    unsigned short* __restrict__ HB,
    float* __restrict__ f1, float* __restrict__ f2) {
  int tid = threadIdx.x, wave = tid >> 6, lane = tid & 63;
  int row0 = blockIdx.x * 64 + wave * 16;
  int cl = lane & 15, kb = lane >> 4;
  f32x4 acc0 = {0.f,0.f,0.f,0.f}, acc1 = {0.f,0.f,0.f,0.f};
  f32x4 acc2 = {0.f,0.f,0.f,0.f}, acc3 = {0.f,0.f,0.f,0.f};
  float s1 = 0.f, s2 = 0.f;
  const float* xrow = X + (size_t)(row0 + cl) * INF_ + kb * 8;
  const bf16x8* BH = (const bf16x8*)Wbhi + lane;
  const bf16x8* BL = (const bf16x8*)Wblo + lane;
#pragma unroll 4
  for (int s = 0; s < 16; ++s) {
    fx4 x0 = *(const fx4*)(xrow + s * 32);
    fx4 x1 = *(const fx4*)(xrow + s * 32 + 4);
    const float* wp1 = Wa1 + kb * 8 + s * 32;
    const float* wp2 = Wa2 + kb * 8 + s * 32;
    fx4 w10 = *(const fx4*)(wp1), w11 = *(const fx4*)(wp1 + 4);
    fx4 w20 = *(const fx4*)(wp2), w21 = *(const fx4*)(wp2 + 4);
    bf16x8 ah, al;
#pragma unroll
    for (int e = 0; e < 4; ++e) {
      float xv = x0[e];
      unsigned short h = f2bf(xv);
      unsigned short l = f2bf(xv - bf2f(h));
      ah[e] = (short)h; al[e] = (short)l;
      s1 += xv * w10[e]; s2 += xv * w20[e];
    }
#pragma unroll
    for (int e = 0; e < 4; ++e) {
      float xv = x1[e];
      unsigned short h = f2bf(xv);
      unsigned short l = f2bf(xv - bf2f(h));
      ah[4 + e] = (short)h; al[4 + e] = (short)l;
      s1 += xv * w11[e]; s2 += xv * w21[e];
    }
    bf16x8 bh0 = BH[(s * 4 + 0) * 64], bl0 = BL[(s * 4 + 0) * 64];
    bf16x8 bh1 = BH[(s * 4 + 1) * 64], bl1 = BL[(s * 4 + 1) * 64];
    bf16x8 bh2 = BH[(s * 4 + 2) * 64], bl2 = BL[(s * 4 + 2) * 64];
    bf16x8 bh3 = BH[(s * 4 + 3) * 64], bl3 = BL[(s * 4 + 3) * 64];
    acc0 = __builtin_amdgcn_mfma_f32_16x16x32_bf16(ah, bh0, acc0, 0, 0, 0);
    acc0 = __builtin_amdgcn_mfma_f32_16x16x32_bf16(ah, bl0, acc0, 0, 0, 0);
    acc0 = __builtin_amdgcn_mfma_f32_16x16x32_bf16(al, bh0, acc0, 0, 0, 0);
    acc1 = __builtin_amdgcn_mfma_f32_16x16x32_bf16(ah, bh1, acc1, 0, 0, 0);
    acc1 = __builtin_amdgcn_mfma_f32_16x16x32_bf16(ah, bl1, acc1, 0, 0, 0);
    acc1 = __builtin_amdgcn_mfma_f32_16x16x32_bf16(al, bh1, acc1, 0, 0, 0);
    acc2 = __builtin_amdgcn_mfma_f32_16x16x32_bf16(ah, bh2, acc2, 0, 0, 0);
    acc2 = __builtin_amdgcn_mfma_f32_16x16x32_bf16(ah, bl2, acc2, 0, 0, 0);
    acc2 = __builtin_amdgcn_mfma_f32_16x16x32_bf16(al, bh2, acc2, 0, 0, 0);
    acc3 = __builtin_amdgcn_mfma_f32_16x16x32_bf16(ah, bh3, acc3, 0, 0, 0);
    acc3 = __builtin_amdgcn_mfma_f32_16x16x32_bf16(ah, bl3, acc3, 0, 0, 0);
    acc3 = __builtin_amdgcn_mfma_f32_16x16x32_bf16(al, bh3, acc3, 0, 0, 0);
  }
  s1 += __shfl_xor(s1, 16, 64); s1 += __shfl_xor(s1, 32, 64);
  s2 += __shfl_xor(s2, 16, 64); s2 += __shfl_xor(s2, 32, 64);
  if (kb == 0) { f1[row0 + cl] = s1; f2[row0 + cl] = s2; }
#pragma unroll
  for (int rr = 0; rr < 4; ++rr) {
    int i = row0 + kb * 4 + rr;       // C/D: row = (lane>>4)*4 + reg  [m89/m91]
    int jt = i >> 5, ji = i & 31;
    int lpb = ((ji >> 3) << 4) | cl;  // C/D: col = lane&15
    int b = ji & 7;
    HB[((size_t)((jt * 4 + 0) * 64 + lpb)) * 8 + b] = f2bf(acc0[rr]);
    HB[((size_t)((jt * 4 + 1) * 64 + lpb)) * 8 + b] = f2bf(acc1[rr]);
    HB[((size_t)((jt * 4 + 2) * 64 + lpb)) * 8 + b] = f2bf(acc2[rr]);
    HB[((size_t)((jt * 4 + 3) * 64 + lpb)) * 8 + b] = f2bf(acc3[rr]);
  }
}

// ---------------------------------------------------------------------------
// k2: main GAT kernel.  WG = 16 rows (512 WGs); wave w handles j-quarter.
// Per 32-j tile: lane computes 8 masked exp-weights (= A-frag slots),
// 4 MFMAs accumulate O[16x64]; denominator = sum of bf16-rounded weights.
// 2-deep software pipeline on the tile loads (adj nontemporal).
// ---------------------------------------------------------------------------
__global__ __launch_bounds__(256) void k_gat(
    const int* __restrict__ adj, const float* __restrict__ f1,
    const float* __restrict__ f2, const unsigned short* __restrict__ HB,
    float* __restrict__ out) {
  __shared__ float Olds[4][16][64];
  __shared__ float Llds[4][16];
  int tid = threadIdx.x, wave = tid >> 6, lane = tid & 63;
  int rowbase = blockIdx.x * 16;
  int r = lane & 15, kb = lane >> 4;
  float f1r = f1[rowbase + r];
  f32x4 acc0 = {0.f,0.f,0.f,0.f}, acc1 = {0.f,0.f,0.f,0.f};
  f32x4 acc2 = {0.f,0.f,0.f,0.f}, acc3 = {0.f,0.f,0.f,0.f};
  float lsum = 0.f;
  const int jstart = wave * 2048;
  const size_t arow = (size_t)(rowbase + r) * NROW;
  const bf16x8* hb = (const bf16x8*)HB;

  // prologue: tile 0
  int j0 = jstart + kb * 8;
  i32x4 aa = __builtin_nontemporal_load((const i32x4*)(adj + arow + j0));
  i32x4 ab = __builtin_nontemporal_load((const i32x4*)(adj + arow + j0) + 1);
  fx4 fa = *(const fx4*)(f2 + j0);
  fx4 fb = *(const fx4*)(f2 + j0 + 4);
  int tile = jstart >> 5;
  bf16x8 B0 = hb[(tile * 4 + 0) * 64 + lane];
  bf16x8 B1 = hb[(tile * 4 + 1) * 64 + lane];
  bf16x8 B2 = hb[(tile * 4 + 2) * 64 + lane];
  bf16x8 B3 = hb[(tile * 4 + 3) * 64 + lane];

#pragma unroll 2
  for (int t = 0; t < 64; ++t) {
    int tn = (t + 1) & 63;  // last iter wraps to tile 0 (in-bounds, unused)
    int j0n = jstart + tn * 32 + kb * 8;
    int tn_tile = (jstart + tn * 32) >> 5;
    i32x4 naa = __builtin_nontemporal_load((const i32x4*)(adj + arow + j0n));
    i32x4 nab = __builtin_nontemporal_load((const i32x4*)(adj + arow + j0n) + 1);
    fx4 nfa = *(const fx4*)(f2 + j0n);
    fx4 nfb = *(const fx4*)(f2 + j0n + 4);
    bf16x8 nB0 = hb[(tn_tile * 4 + 0) * 64 + lane];
    bf16x8 nB1 = hb[(tn_tile * 4 + 1) * 64 + lane];
    bf16x8 nB2 = hb[(tn_tile * 4 + 2) * 64 + lane];
    bf16x8 nB3 = hb[(tn_tile * 4 + 3) * 64 + lane];

    bf16x8 A;
#define DO_W(slot, av, fv)                                   \
    {                                                        \
      float s_ = f1r + (fv);                                 \
      s_ = fmaxf(s_, 0.2f * s_);                             \
      float e_ = __expf(s_);                                 \
      e_ = (av) ? e_ : 0.0f;                                 \
      unsigned short h_ = f2bf(e_);                          \
      A[slot] = (short)h_;                                   \
      lsum += bf2f(h_);                                      \
    }
    DO_W(0, aa.x, fa.x) DO_W(1, aa.y, fa.y) DO_W(2, aa.z, fa.z) DO_W(3, aa.w, fa.w)
    DO_W(4, ab.x, fb.x) DO_W(5, ab.y, fb.y) DO_W(6, ab.z, fb.z) DO_W(7, ab.w, fb.w)
#undef DO_W
    acc0 = __builtin_amdgcn_mfma_f32_16x16x32_bf16(A, B0, acc0, 0, 0, 0);
    acc1 = __builtin_amdgcn_mfma_f32_16x16x32_bf16(A, B1, acc1, 0, 0, 0);
    acc2 = __builtin_amdgcn_mfma_f32_16x16x32_bf16(A, B2, acc2, 0, 0, 0);
    acc3 = __builtin_amdgcn_mfma_f32_16x16x32_bf16(A, B3, acc3, 0, 0, 0);
    aa = naa; ab = nab; fa = nfa; fb = nfb;
    B0 = nB0; B1 = nB1; B2 = nB2; B3 = nB3;
  }

  lsum += __shfl_xor(lsum, 16, 64);
  lsum += __shfl_xor(lsum, 32, 64);
#pragma unroll
  for (int rr = 0; rr < 4; ++rr) {
    Olds[wave][kb * 4 + rr][0 * 16 + r] = acc0[rr];
    Olds[wave][kb * 4 + rr][1 * 16 + r] = acc1[rr];
    Olds[wave][kb * 4 + rr][2 * 16 + r] = acc2[rr];
    Olds[wave][kb * 4 + rr][3 * 16 + r] = acc3[rr];
  }
  if (lane < 16) Llds[wave][lane] = lsum;
  __syncthreads();
#pragma unroll
  for (int e = 0; e < 4; ++e) {
    int idx = tid + e * 256;
    int rr = idx >> 6, n = idx & 63;
    float o = Olds[0][rr][n] + Olds[1][rr][n] + Olds[2][rr][n] + Olds[3][rr][n];
    float l = Llds[0][rr] + Llds[1][rr] + Llds[2][rr] + Llds[3][rr];
    out[(size_t)(rowbase + rr) * OUTF + n] = o / l;
  }
}

extern "C" void kernel_launch(void* const* d_in, const int* in_sizes, int n_in,
                              void* d_out, int out_size, void* d_ws, size_t ws_size,
                              hipStream_t stream) {
  const float* X  = (const float*)d_in[0];
  const int* adj  = (const int*)d_in[1];
  const float* W  = (const float*)d_in[2];
  const float* a  = (const float*)d_in[3];
  float* out = (float*)d_out;

  char* ws = (char*)d_ws;
  float* f1            = (float*)(ws);                    // 32 KB
  float* f2            = (float*)(ws + 32768);            // 32 KB
  float* Wa1           = (float*)(ws + 65536);            // 2 KB
  float* Wa2           = (float*)(ws + 67584);            // 2 KB
  unsigned short* Wbhi = (unsigned short*)(ws + 69632);   // 64 KB
  unsigned short* Wblo = (unsigned short*)(ws + 135168);  // 64 KB
  unsigned short* HB   = (unsigned short*)(ws + 200704);  // 1 MB  (total ~1.25 MB)

  k_prep0<<<8, 256, 0, stream>>>(W, a, Wa1, Wa2, Wbhi, Wblo);
  k_hgemm<<<128, 256, 0, stream>>>(X, Wa1, Wa2, Wbhi, Wblo, HB, f1, f2);
  k_gat<<<512, 256, 0, stream>>>(adj, f1, f2, HB, out);
}

// Round 8
// 410.186 us; speedup vs baseline: 1.0796x; 1.0113x over previous
//
#include <hip/hip_runtime.h>
#include <hip/hip_bf16.h>

#define NROW 8192
#define INF_ 512
#define OUTF 64

typedef __attribute__((ext_vector_type(4))) float  f32x4;
typedef __attribute__((ext_vector_type(4))) float  fx4;
typedef __attribute__((ext_vector_type(4))) int    i32x4;
typedef __attribute__((ext_vector_type(8))) short  bf16x8;

static __device__ __forceinline__ unsigned short f2bf(float x) {
  union { float f; unsigned int u; } c; c.f = x;
  unsigned int u = c.u;
  unsigned int r = (u + 0x7fffu + ((u >> 16) & 1u)) >> 16;
  return (unsigned short)r;
}
static __device__ __forceinline__ float bf2f(unsigned short h) {
  union { unsigned int u; float f; } c; c.u = ((unsigned int)h) << 16;
  return c.f;
}

// ---------------------------------------------------------------------------
// k0: Wa1/Wa2 = W @ a1, W @ a2 (fp32 exact score path) + pack W into
// split-bf16 B-fragment-linear layout.  Shared A/B placement convention:
// tile s, lane = pos + 16*kb, element b <-> contraction index kb*8+b.
// ---------------------------------------------------------------------------
__global__ __launch_bounds__(256) void k_prep0(
    const float* __restrict__ W, const float* __restrict__ a,
    float* __restrict__ Wa1, float* __restrict__ Wa2,
    unsigned short* __restrict__ Wbhi, unsigned short* __restrict__ Wblo) {
  int tid = threadIdx.x, blk = blockIdx.x;  // 8 blocks
  if (tid < 64) {
    int c = blk * 64 + tid;
    const float* wr = W + c * 64;
    float s1 = 0.f, s2 = 0.f;
#pragma unroll
    for (int k = 0; k < 64; ++k) {
      float w = wr[k];
      s1 += w * a[k];
      s2 += w * a[64 + k];
    }
    Wa1[c] = s1; Wa2[c] = s2;
  }
  int base = blk * 4096 + tid * 16;  // linear index into W (c*64+k)
#pragma unroll
  for (int e = 0; e < 16; ++e) {
    int idx = base + e;
    int c = idx >> 6, k = idx & 63;
    float w = W[idx];
    unsigned short h = f2bf(w);
    unsigned short l = f2bf(w - bf2f(h));
    int s = c >> 5, ji = c & 31;
    int lp = ((ji >> 3) << 4) | (k & 15);
    int n16 = k >> 4;
    size_t off = ((size_t)((s * 4 + n16) * 64 + lp)) * 8 + (ji & 7);
    Wbhi[off] = h; Wblo[off] = l;
  }
}

// ---------------------------------------------------------------------------
// k1 (fused): h = X @ W via split-bf16 MFMA (hi*hi + hi*lo + lo*hi) with
// in-register fp32->hi/lo split of X, PLUS exact fp32 f1=X@Wa1, f2=X@Wa2.
// Writes h as bf16 in B-fragment-linear layout HB[(tile*4+n)*64+lane]*8+b.
// ---------------------------------------------------------------------------
__global__ __launch_bounds__(256) void k_hgemm(
    const float* __restrict__ X,
    const float* __restrict__ Wa1, const float* __restrict__ Wa2,
    const unsigned short* __restrict__ Wbhi, const unsigned short* __restrict__ Wblo,
    unsigned short* __restrict__ HB,
    float* __restrict__ f1, float* __restrict__ f2) {
  int tid = threadIdx.x, wave = tid >> 6, lane = tid & 63;
  int row0 = blockIdx.x * 64 + wave * 16;
  int cl = lane & 15, kb = lane >> 4;
  f32x4 acc0 = {0.f,0.f,0.f,0.f}, acc1 = {0.f,0.f,0.f,0.f};
  f32x4 acc2 = {0.f,0.f,0.f,0.f}, acc3 = {0.f,0.f,0.f,0.f};
  float s1 = 0.f, s2 = 0.f;
  const float* xrow = X + (size_t)(row0 + cl) * INF_ + kb * 8;
  const bf16x8* BH = (const bf16x8*)Wbhi + lane;
  const bf16x8* BL = (const bf16x8*)Wblo + lane;
#pragma unroll 4
  for (int s = 0; s < 16; ++s) {
    fx4 x0 = *(const fx4*)(xrow + s * 32);
    fx4 x1 = *(const fx4*)(xrow + s * 32 + 4);
    const float* wp1 = Wa1 + kb * 8 + s * 32;
    const float* wp2 = Wa2 + kb * 8 + s * 32;
    fx4 w10 = *(const fx4*)(wp1), w11 = *(const fx4*)(wp1 + 4);
    fx4 w20 = *(const fx4*)(wp2), w21 = *(const fx4*)(wp2 + 4);
    bf16x8 ah, al;
#pragma unroll
    for (int e = 0; e < 4; ++e) {
      float xv = x0[e];
      unsigned short h = f2bf(xv);
      unsigned short l = f2bf(xv - bf2f(h));
      ah[e] = (short)h; al[e] = (short)l;
      s1 += xv * w10[e]; s2 += xv * w20[e];
    }
#pragma unroll
    for (int e = 0; e < 4; ++e) {
      float xv = x1[e];
      unsigned short h = f2bf(xv);
      unsigned short l = f2bf(xv - bf2f(h));
      ah[4 + e] = (short)h; al[4 + e] = (short)l;
      s1 += xv * w11[e]; s2 += xv * w21[e];
    }
    bf16x8 bh0 = BH[(s * 4 + 0) * 64], bl0 = BL[(s * 4 + 0) * 64];
    bf16x8 bh1 = BH[(s * 4 + 1) * 64], bl1 = BL[(s * 4 + 1) * 64];
    bf16x8 bh2 = BH[(s * 4 + 2) * 64], bl2 = BL[(s * 4 + 2) * 64];
    bf16x8 bh3 = BH[(s * 4 + 3) * 64], bl3 = BL[(s * 4 + 3) * 64];
    acc0 = __builtin_amdgcn_mfma_f32_16x16x32_bf16(ah, bh0, acc0, 0, 0, 0);
    acc0 = __builtin_amdgcn_mfma_f32_16x16x32_bf16(ah, bl0, acc0, 0, 0, 0);
    acc0 = __builtin_amdgcn_mfma_f32_16x16x32_bf16(al, bh0, acc0, 0, 0, 0);
    acc1 = __builtin_amdgcn_mfma_f32_16x16x32_bf16(ah, bh1, acc1, 0, 0, 0);
    acc1 = __builtin_amdgcn_mfma_f32_16x16x32_bf16(ah, bl1, acc1, 0, 0, 0);
    acc1 = __builtin_amdgcn_mfma_f32_16x16x32_bf16(al, bh1, acc1, 0, 0, 0);
    acc2 = __builtin_amdgcn_mfma_f32_16x16x32_bf16(ah, bh2, acc2, 0, 0, 0);
    acc2 = __builtin_amdgcn_mfma_f32_16x16x32_bf16(ah, bl2, acc2, 0, 0, 0);
    acc2 = __builtin_amdgcn_mfma_f32_16x16x32_bf16(al, bh2, acc2, 0, 0, 0);
    acc3 = __builtin_amdgcn_mfma_f32_16x16x32_bf16(ah, bh3, acc3, 0, 0, 0);
    acc3 = __builtin_amdgcn_mfma_f32_16x16x32_bf16(ah, bl3, acc3, 0, 0, 0);
    acc3 = __builtin_amdgcn_mfma_f32_16x16x32_bf16(al, bh3, acc3, 0, 0, 0);
  }
  s1 += __shfl_xor(s1, 16, 64); s1 += __shfl_xor(s1, 32, 64);
  s2 += __shfl_xor(s2, 16, 64); s2 += __shfl_xor(s2, 32, 64);
  if (kb == 0) { f1[row0 + cl] = s1; f2[row0 + cl] = s2; }
#pragma unroll
  for (int rr = 0; rr < 4; ++rr) {
    int i = row0 + kb * 4 + rr;       // C/D: row = (lane>>4)*4 + reg  [m89/m91]
    int jt = i >> 5, ji = i & 31;
    int lpb = ((ji >> 3) << 4) | cl;  // C/D: col = lane&15
    int b = ji & 7;
    HB[((size_t)((jt * 4 + 0) * 64 + lpb)) * 8 + b] = f2bf(acc0[rr]);
    HB[((size_t)((jt * 4 + 1) * 64 + lpb)) * 8 + b] = f2bf(acc1[rr]);
    HB[((size_t)((jt * 4 + 2) * 64 + lpb)) * 8 + b] = f2bf(acc2[rr]);
    HB[((size_t)((jt * 4 + 3) * 64 + lpb)) * 8 + b] = f2bf(acc3[rr]);
  }
}

// ---------------------------------------------------------------------------
// k2: main GAT kernel.  WG = 16 rows (512 WGs); wave w handles j-quarter.
// Per 32-j tile: lane computes 8 masked exp-weights (= A-frag slots),
// 4 MFMAs accumulate O[16x64]; denominator = sum of bf16-rounded weights.
// adj (the HBM stream) is prefetched 2 tiles ahead (3-deep pipeline);
// f2/HB (L2-resident) stay 1 tile ahead.
// ---------------------------------------------------------------------------
__global__ __launch_bounds__(256) void k_gat(
    const int* __restrict__ adj, const float* __restrict__ f1,
    const float* __restrict__ f2, const unsigned short* __restrict__ HB,
    float* __restrict__ out) {
  __shared__ float Olds[4][16][64];
  __shared__ float Llds[4][16];
  int tid = threadIdx.x, wave = tid >> 6, lane = tid & 63;
  int rowbase = blockIdx.x * 16;
  int r = lane & 15, kb = lane >> 4;
  float f1r = f1[rowbase + r];
  f32x4 acc0 = {0.f,0.f,0.f,0.f}, acc1 = {0.f,0.f,0.f,0.f};
  f32x4 acc2 = {0.f,0.f,0.f,0.f}, acc3 = {0.f,0.f,0.f,0.f};
  float lsum = 0.f;
  const int jstart = wave * 2048;
  const size_t arow = (size_t)(rowbase + r) * NROW;
  const bf16x8* hb = (const bf16x8*)HB;
  const int* adjbase = adj + arow + jstart + kb * 8;

  // prologue: adj for tiles 0,1; f2/HB for tile 0
  i32x4 aa0 = __builtin_nontemporal_load((const i32x4*)(adjbase));
  i32x4 ab0 = __builtin_nontemporal_load((const i32x4*)(adjbase) + 1);
  i32x4 aa1 = __builtin_nontemporal_load((const i32x4*)(adjbase + 32));
  i32x4 ab1 = __builtin_nontemporal_load((const i32x4*)(adjbase + 32) + 1);
  int j0 = jstart + kb * 8;
  fx4 fa = *(const fx4*)(f2 + j0);
  fx4 fb = *(const fx4*)(f2 + j0 + 4);
  int tile = jstart >> 5;
  bf16x8 B0 = hb[(tile * 4 + 0) * 64 + lane];
  bf16x8 B1 = hb[(tile * 4 + 1) * 64 + lane];
  bf16x8 B2 = hb[(tile * 4 + 2) * 64 + lane];
  bf16x8 B3 = hb[(tile * 4 + 3) * 64 + lane];

#pragma unroll 2
  for (int t = 0; t < 64; ++t) {
    // adj prefetch 2 ahead (wraps into own range near the end; unused values)
    int t2 = (t + 2) & 63;
    i32x4 aa2 = __builtin_nontemporal_load((const i32x4*)(adjbase + t2 * 32));
    i32x4 ab2 = __builtin_nontemporal_load((const i32x4*)(adjbase + t2 * 32) + 1);
    // f2/HB prefetch 1 ahead (L2-resident)
    int tn = (t + 1) & 63;
    int j0n = jstart + tn * 32 + kb * 8;
    int tn_tile = (jstart + tn * 32) >> 5;
    fx4 nfa = *(const fx4*)(f2 + j0n);
    fx4 nfb = *(const fx4*)(f2 + j0n + 4);
    bf16x8 nB0 = hb[(tn_tile * 4 + 0) * 64 + lane];
    bf16x8 nB1 = hb[(tn_tile * 4 + 1) * 64 + lane];
    bf16x8 nB2 = hb[(tn_tile * 4 + 2) * 64 + lane];
    bf16x8 nB3 = hb[(tn_tile * 4 + 3) * 64 + lane];

    bf16x8 A;
#define DO_W(slot, av, fv)                                   \
    {                                                        \
      float s_ = f1r + (fv);                                 \
      s_ = fmaxf(s_, 0.2f * s_);                             \
      float e_ = __expf(s_);                                 \
      e_ = (av) ? e_ : 0.0f;                                 \
      unsigned short h_ = f2bf(e_);                          \
      A[slot] = (short)h_;                                   \
      lsum += bf2f(h_);                                      \
    }
    DO_W(0, aa0.x, fa.x) DO_W(1, aa0.y, fa.y) DO_W(2, aa0.z, fa.z) DO_W(3, aa0.w, fa.w)
    DO_W(4, ab0.x, fb.x) DO_W(5, ab0.y, fb.y) DO_W(6, ab0.z, fb.z) DO_W(7, ab0.w, fb.w)
#undef DO_W
    acc0 = __builtin_amdgcn_mfma_f32_16x16x32_bf16(A, B0, acc0, 0, 0, 0);
    acc1 = __builtin_amdgcn_mfma_f32_16x16x32_bf16(A, B1, acc1, 0, 0, 0);
    acc2 = __builtin_amdgcn_mfma_f32_16x16x32_bf16(A, B2, acc2, 0, 0, 0);
    acc3 = __builtin_amdgcn_mfma_f32_16x16x32_bf16(A, B3, acc3, 0, 0, 0);
    aa0 = aa1; ab0 = ab1; aa1 = aa2; ab1 = ab2;
    fa = nfa; fb = nfb;
    B0 = nB0; B1 = nB1; B2 = nB2; B3 = nB3;
  }

  lsum += __shfl_xor(lsum, 16, 64);
  lsum += __shfl_xor(lsum, 32, 64);
#pragma unroll
  for (int rr = 0; rr < 4; ++rr) {
    Olds[wave][kb * 4 + rr][0 * 16 + r] = acc0[rr];
    Olds[wave][kb * 4 + rr][1 * 16 + r] = acc1[rr];
    Olds[wave][kb * 4 + rr][2 * 16 + r] = acc2[rr];
    Olds[wave][kb * 4 + rr][3 * 16 + r] = acc3[rr];
  }
  if (lane < 16) Llds[wave][lane] = lsum;
  __syncthreads();
#pragma unroll
  for (int e = 0; e < 4; ++e) {
    int idx = tid + e * 256;
    int rr = idx >> 6, n = idx & 63;
    float o = Olds[0][rr][n] + Olds[1][rr][n] + Olds[2][rr][n] + Olds[3][rr][n];
    float l = Llds[0][rr] + Llds[1][rr] + Llds[2][rr] + Llds[3][rr];
    out[(size_t)(rowbase + rr) * OUTF + n] = o / l;
  }
}

extern "C" void kernel_launch(void* const* d_in, const int* in_sizes, int n_in,
                              void* d_out, int out_size, void* d_ws, size_t ws_size,
                              hipStream_t stream) {
  const float* X  = (const float*)d_in[0];
  const int* adj  = (const int*)d_in[1];
  const float* W  = (const float*)d_in[2];
  const float* a  = (const float*)d_in[3];
  float* out = (float*)d_out;

  char* ws = (char*)d_ws;
  float* f1            = (float*)(ws);                    // 32 KB
  float* f2            = (float*)(ws + 32768);            // 32 KB
  float* Wa1           = (float*)(ws + 65536);            // 2 KB
  float* Wa2           = (float*)(ws + 67584);            // 2 KB
  unsigned short* Wbhi = (unsigned short*)(ws + 69632);   // 64 KB
  unsigned short* Wblo = (unsigned short*)(ws + 135168);  // 64 KB
  unsigned short* HB   = (unsigned short*)(ws + 200704);  // 1 MB  (total ~1.25 MB)

  k_prep0<<<8, 256, 0, stream>>>(W, a, Wa1, Wa2, Wbhi, Wblo);
  k_hgemm<<<128, 256, 0, stream>>>(X, Wa1, Wa2, Wbhi, Wblo, HB, f1, f2);
  k_gat<<<512, 256, 0, stream>>>(adj, f1, f2, HB, out);
}